// Round 1
// baseline (331.850 us; speedup 1.0000x reference)
//
#include <hip/hip_runtime.h>
#include <hip/hip_bf16.h>
#include <cstdint>

#define NROWS 1000000
#define NCLS  128
#define NBINS 15

// conf in (1/128, 1) strictly for this data; cover [2^-9, 1] to be safe.
#define FBASE 0x3B000000u
#define NB    73728          // (0x3F800000 - 0x3B000000) >> 10
#define SCAN_T 1024
#define PER   (NB / SCAN_T)  // 72

// workspace layout (bytes)
#define OFF_CONF   0u
#define OFF_ACC    4000000u
#define OFF_HIST   5000000u
#define OFF_SUB    5294912u   // 30 slots * 1024 u32
#define OFF_BINS   5417792u   // 45 doubles: cnt[15], csum[15], asum[15]
#define OFF_TGTB   5418152u
#define OFF_TGTL   5418272u
#define OFF_EDGES  5418392u
#define ZERO_BYTES (OFF_TGTB - OFF_HIST)   // hist + subhist + bins

// ---------------- kernel 1: per-row conf/acc + coarse histogram ----------------
__global__ __launch_bounds__(256) void k_row(const float* __restrict__ logits,
                                             const int* __restrict__ labels,
                                             float* __restrict__ conf,
                                             unsigned char* __restrict__ acc,
                                             unsigned int* __restrict__ hist)
{
    const int half = threadIdx.x >> 5;     // 8 half-waves per 256-thread block
    const int lane = threadIdx.x & 31;
    const long long row = (long long)blockIdx.x * 8 + half;  // grid exact: 1e6/8

    const float4 v = *reinterpret_cast<const float4*>(logits + row * NCLS + lane * 4);

    // local max + first-index tiebreak (matches jnp.argmax)
    float m = v.x; int mi = lane * 4;
    if (v.y > m) { m = v.y; mi = lane * 4 + 1; }
    if (v.z > m) { m = v.z; mi = lane * 4 + 2; }
    if (v.w > m) { m = v.w; mi = lane * 4 + 3; }
#pragma unroll
    for (int d = 1; d < 32; d <<= 1) {
        float om = __shfl_xor(m, d);
        int   oi = __shfl_xor(mi, d);
        if (om > m || (om == m && oi < mi)) { m = om; mi = oi; }
    }
    float s = __expf(v.x - m) + __expf(v.y - m) + __expf(v.z - m) + __expf(v.w - m);
#pragma unroll
    for (int d = 1; d < 32; d <<= 1) s += __shfl_xor(s, d);

    if (lane == 0) {
        float c = 1.0f / s;                 // max softmax prob
        conf[row] = c;
        acc[row]  = (labels[row] == mi) ? 1u : 0u;
        int ub = (int)(__float_as_uint(c) - FBASE);
        int b  = ub >> 10;
        b = b < 0 ? 0 : (b >= NB ? NB - 1 : b);
        atomicAdd(&hist[b], 1u);
    }
}

// ---------------- kernel 2: scan histogram, locate 30 target ranks ----------------
__device__ __forceinline__ unsigned int rank_of(int s)
{
    if (s == 0)  return 0u;
    if (s == 29) return (unsigned int)(NROWS - 1);
    int i = (s + 1) >> 1;                              // 1..14
    unsigned int k = (unsigned int)((long long)i * NROWS / 15);  // floor(i*N/15)
    return k + ((s & 1) ? 0u : 1u);                    // odd slot: k, even slot: k+1
}

__global__ __launch_bounds__(SCAN_T) void k_scan(const unsigned int* __restrict__ hist,
                                                 int* __restrict__ tgtb,
                                                 int* __restrict__ tgtl)
{
    __shared__ unsigned int lsum[SCAN_T];
    __shared__ unsigned int lpre[SCAN_T];
    const int t = threadIdx.x;
    unsigned int s = 0;
    for (int j = 0; j < PER; j++) s += hist[t * PER + j];
    lsum[t] = s;
    __syncthreads();
    if (t == 0) {
        unsigned int run = 0;
        for (int i = 0; i < SCAN_T; i++) { lpre[i] = run; run += lsum[i]; }
    }
    __syncthreads();
    unsigned int run = lpre[t];
    for (int j = 0; j < PER; j++) {
        unsigned int c = hist[t * PER + j];
        if (c) {
            for (int s2 = 0; s2 < 30; s2++) {
                unsigned int r = rank_of(s2);
                if (r >= run && r < run + c) { tgtb[s2] = t * PER + j; tgtl[s2] = (int)(r - run); }
            }
        }
        run += c;
    }
}

// ---------------- kernel 3: sub-histogram (low 10 bits) for target buckets ----------------
__global__ __launch_bounds__(256) void k_subhist(const float* __restrict__ conf,
                                                 const int* __restrict__ tgtb,
                                                 unsigned int* __restrict__ sub)
{
    __shared__ int tb[30];
    if (threadIdx.x < 30) tb[threadIdx.x] = tgtb[threadIdx.x];
    __syncthreads();
    const int stride = gridDim.x * blockDim.x;
    for (int i = blockIdx.x * blockDim.x + threadIdx.x; i < NROWS / 4; i += stride) {
        float4 c4 = reinterpret_cast<const float4*>(conf)[i];
        float cv[4] = {c4.x, c4.y, c4.z, c4.w};
#pragma unroll
        for (int e = 0; e < 4; e++) {
            int ub = (int)(__float_as_uint(cv[e]) - FBASE);
            int b  = ub >> 10;
            b = b < 0 ? 0 : (b >= NB ? NB - 1 : b);
            int lo = ub & 1023;
            for (int s = 0; s < 30; s++)
                if (b == tb[s]) atomicAdd(&sub[s * 1024 + lo], 1u);
        }
    }
}

// ---------------- kernel 4: resolve exact order-stat values, build edges ----------------
__global__ void k_edges(const unsigned int* __restrict__ sub,
                        const int* __restrict__ tgtb,
                        const int* __restrict__ tgtl,
                        float* __restrict__ edges)
{
    __shared__ float val[30];
    const int t = threadIdx.x;
    if (t < 30) {
        unsigned int local = (unsigned int)tgtl[t];
        unsigned int run = 0;
        int subidx = 0;
        for (int j = 0; j < 1024; j++) {
            unsigned int c = sub[t * 1024 + j];
            if (local >= run && local < run + c) subidx = j;
            run += c;
        }
        unsigned int bits = FBASE + ((unsigned int)tgtb[t] << 10) + (unsigned int)subidx;
        val[t] = __uint_as_float(bits);
    }
    __syncthreads();
    if (t == 0) {
        edges[0]  = val[0];
        edges[15] = val[29];
        for (int i = 1; i <= 14; i++) {
            double q = (double)i * (double)NROWS / 15.0;
            long long k = (long long)i * NROWS / 15;
            double f = q - (double)k;
            edges[i] = (float)((1.0 - f) * (double)val[2 * i - 1] + f * (double)val[2 * i]);
        }
    }
}

// ---------------- kernel 5: bin counts / conf-sums / acc-sums ----------------
__global__ __launch_bounds__(256) void k_bin(const float* __restrict__ conf,
                                             const unsigned char* __restrict__ acc,
                                             const float* __restrict__ edges,
                                             double* __restrict__ bins)
{
    __shared__ float se[16];
    __shared__ float lc[15], ls[15], la[15];
    if (threadIdx.x < 16) se[threadIdx.x] = edges[threadIdx.x];
    if (threadIdx.x < 15) { lc[threadIdx.x] = 0.f; ls[threadIdx.x] = 0.f; la[threadIdx.x] = 0.f; }
    __syncthreads();
    const int stride = gridDim.x * blockDim.x;
    for (int i = blockIdx.x * blockDim.x + threadIdx.x; i < NROWS / 4; i += stride) {
        float4 c4 = reinterpret_cast<const float4*>(conf)[i];
        uchar4 a4 = reinterpret_cast<const uchar4*>(acc)[i];
        float cv[4] = {c4.x, c4.y, c4.z, c4.w};
        unsigned char av[4] = {a4.x, a4.y, a4.z, a4.w};
#pragma unroll
        for (int e = 0; e < 4; e++) {
            float v = cv[e];
            if (v > se[0] && v <= se[15]) {       // valid; else dropped (segment 15)
                int idx = 0;
#pragma unroll
                for (int j = 1; j <= 14; j++) idx += (se[j] < v) ? 1 : 0;  // searchsorted left
                atomicAdd(&lc[idx], 1.0f);
                atomicAdd(&ls[idx], v);
                atomicAdd(&la[idx], (float)av[e]);
            }
        }
    }
    __syncthreads();
    if (threadIdx.x < 15) {
        atomicAdd(&bins[threadIdx.x],      (double)lc[threadIdx.x]);
        atomicAdd(&bins[15 + threadIdx.x], (double)ls[threadIdx.x]);
        atomicAdd(&bins[30 + threadIdx.x], (double)la[threadIdx.x]);
    }
}

// ---------------- kernel 6: final ECE ----------------
__global__ void k_final(const double* __restrict__ bins, float* __restrict__ out)
{
    if (threadIdx.x == 0 && blockIdx.x == 0) {
        double ece = 0.0;
        for (int b = 0; b < NBINS; b++) {
            double cnt = bins[b];
            if (cnt > 0.0) {
                double safe = cnt < 1.0 ? 1.0 : cnt;
                double gap  = fabs(bins[15 + b] / safe - bins[30 + b] / safe);
                ece += gap * (cnt / (double)NROWS);
            }
        }
        out[0] = (float)ece;
    }
}

extern "C" void kernel_launch(void* const* d_in, const int* in_sizes, int n_in,
                              void* d_out, int out_size, void* d_ws, size_t ws_size,
                              hipStream_t stream)
{
    const float* logits = (const float*)d_in[0];
    const int*   labels = (const int*)d_in[1];
    char* ws = (char*)d_ws;

    float*         conf  = (float*)(ws + OFF_CONF);
    unsigned char* acc   = (unsigned char*)(ws + OFF_ACC);
    unsigned int*  hist  = (unsigned int*)(ws + OFF_HIST);
    unsigned int*  sub   = (unsigned int*)(ws + OFF_SUB);
    double*        bins  = (double*)(ws + OFF_BINS);
    int*           tgtb  = (int*)(ws + OFF_TGTB);
    int*           tgtl  = (int*)(ws + OFF_TGTL);
    float*         edges = (float*)(ws + OFF_EDGES);

    hipMemsetAsync(ws + OFF_HIST, 0, ZERO_BYTES, stream);

    k_row<<<NROWS / 8, 256, 0, stream>>>(logits, labels, conf, acc, hist);
    k_scan<<<1, SCAN_T, 0, stream>>>(hist, tgtb, tgtl);
    k_subhist<<<1024, 256, 0, stream>>>(conf, tgtb, sub);
    k_edges<<<1, 32, 0, stream>>>(sub, tgtb, tgtl, edges);
    k_bin<<<1024, 256, 0, stream>>>(conf, acc, edges, bins);
    k_final<<<1, 64, 0, stream>>>(bins, (float*)d_out);
}

// Round 2
// 227.760 us; speedup vs baseline: 1.4570x; 1.4570x over previous
//
#include <hip/hip_runtime.h>
#include <hip/hip_bf16.h>
#include <cstdint>

#define NROWS 1000000
#define NCLS  128
#define NBINS 15

// conf in (1/128, 1) strictly for this data; cover [2^-9, 1] to be safe.
#define FBASE 0x3B000000u
#define NB    73728          // (0x3F800000 - 0x3B000000) >> 10
#define SCAN_T 1024
#define PER   (NB / SCAN_T)  // 72

// workspace layout (bytes)
#define OFF_CONF   0u
#define OFF_ACC    4000000u
#define OFF_HIST   5000000u
#define OFF_SUB    5294912u   // 30 slots * 1024 u32
#define OFF_BINS   5417792u   // 45 doubles: cnt[15], csum[15], asum[15]
#define OFF_TGTB   5418152u
#define OFF_TGTL   5418272u
#define OFF_EDGES  5418392u
#define ZERO_BYTES (OFF_TGTB - OFF_HIST)   // hist + subhist + bins

#define ROWS_PER_BLOCK 32     // 4 waves * 8 rows (2 per 16-lane group)

// ---------------- kernel 1: per-row conf/acc + coarse histogram ----------------
__device__ __forceinline__ void reduce_row(float4 v0, float4 v1, int l16,
                                           float& c_out, int& mi_out)
{
    const int b0 = l16 * 4, b1 = 64 + l16 * 4;
    float m = v0.x; int mi = b0;
    if (v0.y > m) { m = v0.y; mi = b0 + 1; }
    if (v0.z > m) { m = v0.z; mi = b0 + 2; }
    if (v0.w > m) { m = v0.w; mi = b0 + 3; }
    if (v1.x > m) { m = v1.x; mi = b1; }
    if (v1.y > m) { m = v1.y; mi = b1 + 1; }
    if (v1.z > m) { m = v1.z; mi = b1 + 2; }
    if (v1.w > m) { m = v1.w; mi = b1 + 3; }
#pragma unroll
    for (int d = 1; d < 16; d <<= 1) {          // stays within 16-lane group
        float om = __shfl_xor(m, d);
        int   oi = __shfl_xor(mi, d);
        if (om > m || (om == m && oi < mi)) { m = om; mi = oi; }
    }
    float s = __expf(v0.x - m) + __expf(v0.y - m) + __expf(v0.z - m) + __expf(v0.w - m)
            + __expf(v1.x - m) + __expf(v1.y - m) + __expf(v1.z - m) + __expf(v1.w - m);
#pragma unroll
    for (int d = 1; d < 16; d <<= 1) s += __shfl_xor(s, d);
    c_out  = 1.0f / s;
    mi_out = mi;
}

__global__ __launch_bounds__(256) void k_row(const float* __restrict__ logits,
                                             const int* __restrict__ labels,
                                             float* __restrict__ conf,
                                             unsigned char* __restrict__ acc,
                                             unsigned int* __restrict__ hist)
{
    const int wave = threadIdx.x >> 6;
    const int lane = threadIdx.x & 63;
    const int sub  = lane >> 4;        // row slot within wave (0..3)
    const int l16  = lane & 15;
    const long long base = (long long)blockIdx.x * ROWS_PER_BLOCK + wave * 8;
    const long long rowA = base + sub;
    const long long rowB = base + 4 + sub;

    // 4 independent 16B loads issued before any use -> high MLP
    const float4* pA = reinterpret_cast<const float4*>(logits + rowA * NCLS);
    const float4* pB = reinterpret_cast<const float4*>(logits + rowB * NCLS);
    const float4 a0 = pA[l16];
    const float4 a1 = pA[16 + l16];
    const float4 b0 = pB[l16];
    const float4 b1 = pB[16 + l16];
    const int labA = labels[rowA];   // broadcast within 16-lane group
    const int labB = labels[rowB];

    float cA, cB; int miA, miB;
    reduce_row(a0, a1, l16, cA, miA);
    reduce_row(b0, b1, l16, cB, miB);

    if (l16 == 0) {
        conf[rowA] = cA;
        acc[rowA]  = (labA == miA) ? 1u : 0u;
        int ubA = (int)(__float_as_uint(cA) - FBASE);
        int bA  = ubA >> 10;
        bA = bA < 0 ? 0 : (bA >= NB ? NB - 1 : bA);
        atomicAdd(&hist[bA], 1u);

        conf[rowB] = cB;
        acc[rowB]  = (labB == miB) ? 1u : 0u;
        int ubB = (int)(__float_as_uint(cB) - FBASE);
        int bB  = ubB >> 10;
        bB = bB < 0 ? 0 : (bB >= NB ? NB - 1 : bB);
        atomicAdd(&hist[bB], 1u);
    }
}

// ---------------- kernel 2: scan histogram, locate 30 target ranks ----------------
__device__ __forceinline__ unsigned int rank_of(int s)
{
    if (s == 0)  return 0u;
    if (s == 29) return (unsigned int)(NROWS - 1);
    int i = (s + 1) >> 1;                              // 1..14
    unsigned int k = (unsigned int)((long long)i * NROWS / 15);  // floor(i*N/15)
    return k + ((s & 1) ? 0u : 1u);                    // odd slot: k, even slot: k+1
}

__global__ __launch_bounds__(SCAN_T) void k_scan(const unsigned int* __restrict__ hist,
                                                 int* __restrict__ tgtb,
                                                 int* __restrict__ tgtl)
{
    __shared__ unsigned int v[SCAN_T];
    const int t = threadIdx.x;
    unsigned int s = 0;
    for (int j = 0; j < PER; j++) s += hist[t * PER + j];
    v[t] = s;
    __syncthreads();
    // Hillis-Steele inclusive scan over 1024 chunk sums
    for (int off = 1; off < SCAN_T; off <<= 1) {
        unsigned int x = (t >= off) ? v[t - off] : 0u;
        __syncthreads();
        v[t] += x;
        __syncthreads();
    }
    const unsigned int run0 = v[t] - s;   // exclusive prefix of this thread's chunk
    for (int s2 = 0; s2 < 30; s2++) {
        unsigned int r = rank_of(s2);
        if (r >= run0 && r < run0 + s) {  // rank falls in my chunk: walk it
            unsigned int run = run0;
            for (int j = 0; j < PER; j++) {
                unsigned int c = hist[t * PER + j];
                if (r < run + c) { tgtb[s2] = t * PER + j; tgtl[s2] = (int)(r - run); break; }
                run += c;
            }
        }
    }
}

// ---------------- kernel 3: sub-histogram (low 10 bits) for target buckets ----------------
__global__ __launch_bounds__(256) void k_subhist(const float* __restrict__ conf,
                                                 const int* __restrict__ tgtb,
                                                 unsigned int* __restrict__ sub)
{
    __shared__ int tb[30];
    if (threadIdx.x < 30) tb[threadIdx.x] = tgtb[threadIdx.x];
    __syncthreads();
    const int stride = gridDim.x * blockDim.x;
    for (int i = blockIdx.x * blockDim.x + threadIdx.x; i < NROWS / 4; i += stride) {
        float4 c4 = reinterpret_cast<const float4*>(conf)[i];
        float cv[4] = {c4.x, c4.y, c4.z, c4.w};
#pragma unroll
        for (int e = 0; e < 4; e++) {
            int ub = (int)(__float_as_uint(cv[e]) - FBASE);
            int b  = ub >> 10;
            b = b < 0 ? 0 : (b >= NB ? NB - 1 : b);
            int lo = ub & 1023;
            for (int s = 0; s < 30; s++)
                if (b == tb[s]) atomicAdd(&sub[s * 1024 + lo], 1u);
        }
    }
}

// ---------------- kernel 4: resolve exact order-stat values, build edges ----------------
__global__ __launch_bounds__(1024) void k_edges(const unsigned int* __restrict__ sub,
                        const int* __restrict__ tgtb,
                        const int* __restrict__ tgtl,
                        float* __restrict__ edges)
{
    __shared__ float val[32];
    const int g = threadIdx.x >> 5;    // slot 0..31 (30 used)
    const int k = threadIdx.x & 31;    // lane within slot group
    if (g < 30) {
        const unsigned int local = (unsigned int)tgtl[g];
        unsigned int cs[32];
        unsigned int csum = 0;
        const unsigned int* p = sub + g * 1024 + k * 32;
#pragma unroll
        for (int j = 0; j < 32; j++) { cs[j] = p[j]; csum += cs[j]; }
        // inclusive scan across the 32-lane group (guarded shfl_up)
        unsigned int incl = csum;
#pragma unroll
        for (int off = 1; off < 32; off <<= 1) {
            unsigned int x = __shfl_up(incl, off);
            if (k >= off) incl += x;
        }
        const unsigned int excl = incl - csum;
        if (local >= excl && local < excl + csum) {   // exactly one lane hits
            unsigned int run = excl;
            int subidx = 0;
#pragma unroll
            for (int j = 0; j < 32; j++) {
                if (local >= run && local < run + cs[j]) subidx = k * 32 + j;
                run += cs[j];
            }
            unsigned int bits = FBASE + ((unsigned int)tgtb[g] << 10) + (unsigned int)subidx;
            val[g] = __uint_as_float(bits);
        }
    }
    __syncthreads();
    if (threadIdx.x == 0) {
        edges[0]  = val[0];
        edges[15] = val[29];
        for (int i = 1; i <= 14; i++) {
            double q = (double)i * (double)NROWS / 15.0;
            long long kk = (long long)i * NROWS / 15;
            double f = q - (double)kk;
            edges[i] = (float)((1.0 - f) * (double)val[2 * i - 1] + f * (double)val[2 * i]);
        }
    }
}

// ---------------- kernel 5: bin counts / conf-sums / acc-sums ----------------
__global__ __launch_bounds__(256) void k_bin(const float* __restrict__ conf,
                                             const unsigned char* __restrict__ acc,
                                             const float* __restrict__ edges,
                                             double* __restrict__ bins)
{
    __shared__ float se[16];
    __shared__ float lc[4][16], ls[4][16], la[4][16];   // per-wave bins, padded
    const int w = threadIdx.x >> 6;
    if (threadIdx.x < 16) se[threadIdx.x] = edges[threadIdx.x];
    if (threadIdx.x < 64) {
        int a = threadIdx.x >> 4, b = threadIdx.x & 15;
        lc[a][b] = 0.f; ls[a][b] = 0.f; la[a][b] = 0.f;
    }
    __syncthreads();
    const int stride = gridDim.x * blockDim.x;
    for (int i = blockIdx.x * blockDim.x + threadIdx.x; i < NROWS / 4; i += stride) {
        float4 c4 = reinterpret_cast<const float4*>(conf)[i];
        uchar4 a4 = reinterpret_cast<const uchar4*>(acc)[i];
        float cv[4] = {c4.x, c4.y, c4.z, c4.w};
        unsigned char av[4] = {a4.x, a4.y, a4.z, a4.w};
#pragma unroll
        for (int e = 0; e < 4; e++) {
            float v = cv[e];
            if (v > se[0] && v <= se[15]) {       // valid; else dropped
                int idx = 0;
#pragma unroll
                for (int j = 1; j <= 14; j++) idx += (se[j] < v) ? 1 : 0;  // searchsorted left
                atomicAdd(&lc[w][idx], 1.0f);
                atomicAdd(&ls[w][idx], v);
                atomicAdd(&la[w][idx], (float)av[e]);
            }
        }
    }
    __syncthreads();
    if (threadIdx.x < 15) {
        int t = threadIdx.x;
        atomicAdd(&bins[t],      (double)(lc[0][t] + lc[1][t] + lc[2][t] + lc[3][t]));
        atomicAdd(&bins[15 + t], (double)(ls[0][t] + ls[1][t] + ls[2][t] + ls[3][t]));
        atomicAdd(&bins[30 + t], (double)(la[0][t] + la[1][t] + la[2][t] + la[3][t]));
    }
}

// ---------------- kernel 6: final ECE ----------------
__global__ void k_final(const double* __restrict__ bins, float* __restrict__ out)
{
    if (threadIdx.x == 0 && blockIdx.x == 0) {
        double ece = 0.0;
        for (int b = 0; b < NBINS; b++) {
            double cnt = bins[b];
            if (cnt > 0.0) {
                double safe = cnt < 1.0 ? 1.0 : cnt;
                double gap  = fabs(bins[15 + b] / safe - bins[30 + b] / safe);
                ece += gap * (cnt / (double)NROWS);
            }
        }
        out[0] = (float)ece;
    }
}

extern "C" void kernel_launch(void* const* d_in, const int* in_sizes, int n_in,
                              void* d_out, int out_size, void* d_ws, size_t ws_size,
                              hipStream_t stream)
{
    const float* logits = (const float*)d_in[0];
    const int*   labels = (const int*)d_in[1];
    char* ws = (char*)d_ws;

    float*         conf  = (float*)(ws + OFF_CONF);
    unsigned char* acc   = (unsigned char*)(ws + OFF_ACC);
    unsigned int*  hist  = (unsigned int*)(ws + OFF_HIST);
    unsigned int*  sub   = (unsigned int*)(ws + OFF_SUB);
    double*        bins  = (double*)(ws + OFF_BINS);
    int*           tgtb  = (int*)(ws + OFF_TGTB);
    int*           tgtl  = (int*)(ws + OFF_TGTL);
    float*         edges = (float*)(ws + OFF_EDGES);

    hipMemsetAsync(ws + OFF_HIST, 0, ZERO_BYTES, stream);

    k_row<<<NROWS / ROWS_PER_BLOCK, 256, 0, stream>>>(logits, labels, conf, acc, hist);
    k_scan<<<1, SCAN_T, 0, stream>>>(hist, tgtb, tgtl);
    k_subhist<<<1024, 256, 0, stream>>>(conf, tgtb, sub);
    k_edges<<<1, 1024, 0, stream>>>(sub, tgtb, tgtl, edges);
    k_bin<<<1024, 256, 0, stream>>>(conf, acc, edges, bins);
    k_final<<<1, 64, 0, stream>>>(bins, (float*)d_out);
}